// Round 5
// baseline (30677.393 us; speedup 1.0000x reference)
//
#include <hip/hip_runtime.h>

// ESN recurrence on MI355X — R9: R5 structure, register-direct h consume, fp16.
// T=4096 steps, B=64, I=128, H=1024. out = h_T [64,1024] fp32.
//
// Geometry/sync/publish are IDENTICAL to the hardware-validated R5 kernel
// (64 blocks x 256 threads, 4 waves; tag-in-bit-30 self-validating publish;
// scattered per-even-lane dword sc1 stores in per-block 2KB chunk layout
// [16 rows][32 u32]). Diff vs R5 (minimal, each independently justified):
//  1. h_lds staging DELETED: R5's chunk layout already matches the MFMA
//     A-fragment — each wave loads its 32 fragments as tagged dwordx4
//     straight into registers (rbu + (m*16+(kt>>1))*512 + col*32 +
//     (kt&1)*16 + quad*4). Removes the 1.5e8 LDS bank-conflict cycles,
//     barrier #2, and the ds_read->MFMA chain.
//  2. fp16 instead of bf16 hi/lo: 72 -> 36 MFMAs/step, parity-split into
//     two 18-deep chains; MORE accurate (fp16 h: 2^-11 vs bf16 2^-8).
//     Tag invariant survives: fp16 bit14 (exp MSB) == 0 for |v|<2; tanh<1.
//  3. All waits are vmcnt(0)+sched_barrier(0) (no counted FIFO — the R6-R8
//     failure surface). Retry rounds fully drain, bounded 65536 + poison:
//     self-healing under any spill/under-wait, can never hang.
// x path R5-verbatim (plain prefetch loads -> fp16 -> x_lds, barrier #1),
// except x_{t+1} prefetch is issued AFTER the poll's vmcnt(0) so the poll
// never waits on HBM x latency.

#define TT 4096
#define BB 64
#define II 128
#define HH 1024
#define TAGBIT 0x40000000u

typedef _Float16 f16x8 __attribute__((ext_vector_type(8)));
typedef float f32x4 __attribute__((ext_vector_type(4)));
typedef unsigned int u32x4 __attribute__((ext_vector_type(4)));

static __device__ __forceinline__ unsigned short f2h_bits(float f) {
    _Float16 h = (_Float16)f;          // v_cvt_f16_f32 (RNE)
    return __builtin_bit_cast(unsigned short, h);
}

// R5-hardware-proven vaddr-form global ops (64-bit pointer in VGPR pair).
static __device__ __forceinline__ u32x4 gload16_sc1(const unsigned int* p) {
    u32x4 r;
    asm volatile("global_load_dwordx4 %0, %1, off sc1"
                 : "=v"(r) : "v"(p) : "memory");
    return r;
}
static __device__ __forceinline__ void gstore4_sc1(unsigned int* p, unsigned int v) {
    asm volatile("global_store_dword %0, %1, off sc1"
                 :: "v"(p), "v"(v) : "memory");
}

// full drain + scheduler fence (rule #18: sched_barrier after asm waitcnt)
#define WAITV0()                                              \
    asm volatile("s_waitcnt vmcnt(0)" ::: "memory");          \
    __builtin_amdgcn_sched_barrier(0)

// tag-check fragment kt; on pass: clear tag bits + 1 MFMA (parity chain);
// on fail: FAIL action. kt is a compile-time constant at every expansion.
#define CHECK_TILE(kt, FAIL)                                                  \
    {                                                                         \
        u32x4 v = hf[kt];                                                     \
        unsigned int bad = (v[0] ^ etag) | (v[1] ^ etag) |                    \
                           (v[2] ^ etag) | (v[3] ^ etag);                     \
        if (__ballot((bad & TAGBIT) == 0u) == ~0ull) {                        \
            v &= 0xBFFFFFFFu;                                                 \
            f16x8 a = __builtin_bit_cast(f16x8, v);                           \
            (((kt) & 1) ? acc1 : acc0) =                                      \
                __builtin_amdgcn_mfma_f32_16x16x32_f16(                       \
                    a, wh[kt], (((kt) & 1) ? acc1 : acc0), 0, 0, 0);          \
        } else { FAIL; }                                                      \
    }

__global__ __launch_bounds__(256, 1) void esn_kernel(
    const float* __restrict__ x, const float* __restrict__ wih,
    const float* __restrict__ whh, const float* __restrict__ bih,
    const float* __restrict__ bhh, float* __restrict__ out,
    unsigned int* __restrict__ hbu0, unsigned int* __restrict__ hbu1)
{
    __shared__ __align__(16) unsigned short x_lds[16 * 136];   // 4.25 KB

    const int tid  = threadIdx.x;
    const int lane = tid & 63;
    const int wv   = tid >> 6;
    const int col  = lane & 15;     // MFMA col (n) / A row (m)
    const int quad = lane >> 4;

    const int blk    = blockIdx.x;          // 0..63
    const int m      = blk >> 4;            // batch group 0..3
    const int m_base = m * 16;
    const int jj     = blk & 15;            // producer index within group
    const int n_idx  = jj * 4 + wv;
    const int n_base = n_idx * 16;

    // ---- one-time: weights into registers as fp16 (B-fragment layout,
    //      addressing identical to HW-validated R4/R5) ----
    f16x8 wh[32], wi[4];
#pragma unroll
    for (int kt = 0; kt < 32; ++kt) {
        const float* p = whh + (size_t)(n_base + col) * HH + kt * 32 + quad * 8;
        f16x8 w;
#pragma unroll
        for (int j = 0; j < 8; ++j) w[j] = (_Float16)p[j];
        wh[kt] = w;
    }
#pragma unroll
    for (int kt = 0; kt < 4; ++kt) {
        const float* p = wih + (size_t)(n_base + col) * II + kt * 32 + quad * 8;
        f16x8 w;
#pragma unroll
        for (int j = 0; j < 8; ++j) w[j] = (_Float16)p[j];
        wi[kt] = w;
    }
    const float bias_sum = bih[n_base + col] + bhh[n_base + col];

    const int sr = tid >> 4;          // x-staging row 0..15
    const int sc = tid & 15;          // x-staging col group 0..15

    // h fragment base (u32 units): frag kt at hb + (kt>>1)*512 + (kt&1)*16.
    // Derivation: frag kt needs h cols kt*32+quad*8..+7 of row `col` =
    // chunk jj'=(kt>>1), within-chunk u32s (kt&1)*16+quad*4..+3 — 16B aligned.
    // (chunk layout [16 rows][32 u32] is R5's publish layout, unchanged.)
    const float* xg = x + (size_t)(m_base + sr) * II + sc * 8;

    // prefetch x_0 (plain loads; compiler manages the waits — R5-proven mix)
    f32x4 xa, xb;
    xa = *(const f32x4*)xg;
    xb = *(const f32x4*)(xg + 4);

    u32x4 hf[32];
    for (int t = 0; t < TT; ++t) {
        const unsigned int* rbu = (t & 1) ? hbu1 : hbu0;
        unsigned int*       wbu = (t & 1) ? hbu0 : hbu1;
        // tags: producer at step s tags 1^((s>>1)&1); consumer at t expects
        // tag(t-1); zero-init = tag 0. Stale (t-3) data: opposite tag.
        const unsigned int etag =
            (t == 0) ? 0u : ((1u ^ (((unsigned)(t - 1) >> 1) & 1u)) << 30);
        const unsigned int my_tag = (1u ^ (((unsigned)t >> 1) & 1u)) << 30;

        // (1) convert prefetched x_t -> fp16 -> x_lds (R5-verbatim path)
        {
            f16x8 v;
#pragma unroll
            for (int j = 0; j < 4; ++j) v[j] = (_Float16)xa[j];
#pragma unroll
            for (int j = 0; j < 4; ++j) v[4 + j] = (_Float16)xb[j];
            *(f16x8*)(x_lds + sr * 136 + sc * 8) = v;
        }

        // (2) issue all 32 tagged h-fragment loads (register-direct)
        const unsigned int* hb =
            rbu + (size_t)(m * 16) * 512 + col * 32 + quad * 4;
#pragma unroll
        for (int kt = 0; kt < 32; ++kt)
            hf[kt] = gload16_sc1(hb + (kt >> 1) * 512 + (kt & 1) * 16);

        // (3) barrier #1: x_lds ready (LDS-only wait; loads stay in flight)
        asm volatile("s_waitcnt lgkmcnt(0)" ::: "memory");
        __builtin_amdgcn_s_barrier();
        __builtin_amdgcn_sched_barrier(0);

        // (4) x MFMAs fill part of the h-RT shadow
        f32x4 acc0 = {0.f, 0.f, 0.f, 0.f};
        f32x4 acc1 = {0.f, 0.f, 0.f, 0.f};
        const unsigned short* xrow = x_lds + col * 136;
#pragma unroll
        for (int kt = 0; kt < 4; ++kt) {
            f16x8 a = *(const f16x8*)(xrow + kt * 32 + quad * 8);
            ((kt & 1) ? acc1 : acc0) =
                __builtin_amdgcn_mfma_f32_16x16x32_f16(
                    a, wi[kt], ((kt & 1) ? acc1 : acc0), 0, 0, 0);
        }

        // (5) poll: full drain, then tag-check all 32 fragments
        WAITV0();

        // x_{t+1} prefetch — after the drain, so the poll never waits on
        // HBM x latency; it completes under MFMAs/epilogue/next-iter front.
        if (t + 1 < TT) {
            const float* p = xg + (size_t)(t + 1) * (BB * II);
            xa = *(const f32x4*)p;
            xb = *(const f32x4*)(p + 4);
        }

        unsigned int mask = 0;
#pragma unroll
        for (int kt = 0; kt < 32; ++kt) CHECK_TILE(kt, mask |= (1u << kt))

        // (6) retry net: full-drain rounds, bounded + poison — never hangs,
        //     self-healing even if a spill corrupts an in-flight register.
        mask = __builtin_amdgcn_readfirstlane(mask);
        int rounds = 0;
        while (mask && rounds < 65536) {
#pragma unroll
            for (int kt = 0; kt < 32; ++kt)
                if (mask & (1u << kt))
                    hf[kt] = gload16_sc1(hb + (kt >> 1) * 512 + (kt & 1) * 16);
            WAITV0();
            unsigned int nm = 0;
#pragma unroll
            for (int kt = 0; kt < 32; ++kt)
                if (mask & (1u << kt))
                    CHECK_TILE(kt, nm |= (1u << kt))
            mask = __builtin_amdgcn_readfirstlane(nm);
            ++rounds;
        }
        if (mask) acc0[0] += 1e30f;   // protocol failure -> loud, never hung

        // (7) epilogue: bias + tanh (R5-verbatim)
        float th[4];
#pragma unroll
        for (int i = 0; i < 4; ++i) {
            float pre = acc0[i] + acc1[i] + bias_sum;
            float pc  = fminf(fmaxf(pre, -9.f), 9.f);
            float e2  = __expf(2.f * pc);
            th[i] = (e2 - 1.f) / (e2 + 1.f);
        }

        if (t == TT - 1) {
#pragma unroll
            for (int i = 0; i < 4; ++i)
                out[(size_t)(m_base + quad * 4 + i) * HH + n_base + col] = th[i];
        } else {
            // (8) publish — R5-verbatim scattered tagged dword sc1 stores.
            // C/D layout: th[i] = C[row quad*4+i][col]; pair cols (2c,2c+1).
            unsigned int p01 = (unsigned int)f2h_bits(th[0]) |
                               ((unsigned int)f2h_bits(th[1]) << 16);
            unsigned int p23 = (unsigned int)f2h_bits(th[2]) |
                               ((unsigned int)f2h_bits(th[3]) << 16);
            unsigned int q01 = (unsigned int)__shfl_xor((int)p01, 1, 64);
            unsigned int q23 = (unsigned int)__shfl_xor((int)p23, 1, 64);
            if (!(lane & 1)) {
                unsigned int w0 = ((p01 & 0xFFFFu) | (q01 << 16)) | my_tag;
                unsigned int w1 = ((p01 >> 16) | (q01 & 0xFFFF0000u)) | my_tag;
                unsigned int w2 = ((p23 & 0xFFFFu) | (q23 << 16)) | my_tag;
                unsigned int w3 = ((p23 >> 16) | (q23 & 0xFFFF0000u)) | my_tag;
                unsigned int* bp = wbu + (size_t)(m * 16 + jj) * 512
                                   + wv * 8 + (col >> 1);
                gstore4_sc1(bp + (quad * 4 + 0) * 32, w0);
                gstore4_sc1(bp + (quad * 4 + 1) * 32, w1);
                gstore4_sc1(bp + (quad * 4 + 2) * 32, w2);
                gstore4_sc1(bp + (quad * 4 + 3) * 32, w3);
            }
            // fire-and-forget: tags make the data self-validating
        }
    }
}

extern "C" void kernel_launch(void* const* d_in, const int* in_sizes, int n_in,
                              void* d_out, int out_size, void* d_ws, size_t ws_size,
                              hipStream_t stream) {
    const float* x   = (const float*)d_in[0];
    const float* wih = (const float*)d_in[1];
    const float* whh = (const float*)d_in[2];
    const float* bih = (const float*)d_in[3];
    const float* bhh = (const float*)d_in[4];
    float* out = (float*)d_out;

    unsigned int* hbu0 = (unsigned int*)d_ws;                      // 128 KB
    unsigned int* hbu1 = hbu0 + 32768;                             // 128 KB

    // zero both h buffers: h0 = 0 payload, tag bits 0 (ws is poisoned 0xAA)
    hipMemsetAsync(d_ws, 0, 262144, stream);

    esn_kernel<<<dim3(64), dim3(256), 0, stream>>>(x, wih, whh, bih, bhh,
                                                   out, hbu0, hbu1);
}